// Round 6
// baseline (769.957 us; speedup 1.0000x reference)
//
#include <hip/hip_runtime.h>
#include <stdint.h>

// ---------------------------------------------------------------------------
// aggregated_embedding: heap binary-tree aggregation, 11 levels.
// Per level: out = root + (elu(elu(x@WinT+b_in)@W1T+b1)@W2T+b2), x=[root,left,right]
// bf16 MFMA 16x16x32, fp32 accumulate. Round 8:
//  R5 post-mortem: chunked stage REGRESSED (95->143us; 16-deep MLP mattered,
//  WRITE excess unchanged => not stage spill) and MT=8-on-tiny-grids
//  REGRESSED (+90us). Both reverted to R4 exactly.
//  NEW: tree_tail fuses ALL levels L=128..1 into ONE dispatch. Tree is
//  independent per batch => block b owns batch b's subtree; inter-level
//  intermediate (<=128 rows) lives in LDS (Pv region, 65KB); left/right
//  gathers become LDS reads; 8 dispatches + global round-trips + weight
//  re-streams collapse into one ~40us kernel. Rows i>=L are clamped
//  duplicates (outputs masked) so the MFMA structure stays compile-time.
// schedule: convert | L=1024 MT8 | L=512 MT8 | L=256 MT2 | tail(128..1)
// ws layout:
//   [0)            Ebf   32064*256 bf16
//   [16,416,768)   Winbf 256*768  bf16   (row-major [n][k] = MFMA B-frag order)
//   [16,809,984)   W1bf  256*256  bf16
//   [16,941,056)   W2bf  256*256  bf16
//   [17,072,128)   curA  64*1024*256 bf16
//   [50,626,560)   curB  64*512*256 bf16
// ---------------------------------------------------------------------------

typedef __attribute__((ext_vector_type(8))) short short8;   // 8 x bf16 frag
typedef __attribute__((ext_vector_type(4))) float f32x4;    // MFMA C/D

#define XS_STRIDE 264   // 256+8 pad: row stride 528B, b128-aligned, 2-way bank alias (free)
#define TOK_N 4095

__device__ __forceinline__ unsigned short f32_to_bf16(float f) {
    union { float f; unsigned u; } v; v.f = f;
    return (unsigned short)((v.u + 0x7fffu + ((v.u >> 16) & 1u)) >> 16);  // RNE
}
__device__ __forceinline__ float bf16_to_f32(unsigned short u) {
    union { unsigned u; float f; } v; v.u = ((unsigned)u) << 16; return v.f;
}

__global__ void convert_f32_bf16(const float* __restrict__ E,
                                 const float* __restrict__ Win,
                                 const float* __restrict__ W1,
                                 const float* __restrict__ W2,
                                 unsigned short* __restrict__ Ebf,
                                 unsigned short* __restrict__ Winbf,
                                 unsigned short* __restrict__ W1bf,
                                 unsigned short* __restrict__ W2bf) {
    const int nE = 32064 * 256, nWin = 256 * 768, nW = 256 * 256;
    const int total4 = (nE + nWin + 2 * nW) >> 2;
    for (int i = blockIdx.x * blockDim.x + threadIdx.x; i < total4;
         i += gridDim.x * blockDim.x) {
        int idx = i << 2;
        const float* src; unsigned short* dst; int off;
        if (idx < nE)                  { src = E;   dst = Ebf;   off = idx; }
        else if (idx < nE + nWin)      { src = Win; dst = Winbf; off = idx - nE; }
        else if (idx < nE + nWin + nW) { src = W1;  dst = W1bf;  off = idx - nE - nWin; }
        else                           { src = W2;  dst = W2bf;  off = idx - nE - nWin - nW; }
        float4 f = *(const float4*)(src + off);
        ushort4 o;
        o.x = f32_to_bf16(f.x); o.y = f32_to_bf16(f.y);
        o.z = f32_to_bf16(f.z); o.w = f32_to_bf16(f.w);
        *(ushort4*)(dst + off) = o;
    }
}

// ---- shared GEMM machinery (inlined into both kernels) --------------------
template<int MT>
__device__ __forceinline__ void acc_bias_init(f32x4 (&acc)[MT][4],
                                              const float* __restrict__ b,
                                              int n0, int l15) {
    float bv[4];
#pragma unroll
    for (int nt = 0; nt < 4; ++nt) bv[nt] = b[n0 + nt * 16 + l15];
#pragma unroll
    for (int mt = 0; mt < MT; ++mt)
#pragma unroll
        for (int nt = 0; nt < 4; ++nt)
            acc[mt][nt] = (f32x4){bv[nt], bv[nt], bv[nt], bv[nt]};
}

// 8 ksteps of K=256 against a [n][k] weight panel; rolling 2-kstep preload
template<int MT>
__device__ __forceinline__ void mfma_gemm(const unsigned short* Xs,
                                          f32x4 (&acc)[MT][4],
                                          const unsigned short* __restrict__ base,
                                          int nstride, int kbase,
                                          int l15, int q) {
    short8 bb[2][4];
#pragma unroll
    for (int k = 0; k < 2; ++k)
#pragma unroll
        for (int nt = 0; nt < 4; ++nt)
            bb[k][nt] = *(const short8*)(base + (size_t)(nt * 16) * nstride + kbase + k * 32);
#pragma unroll
    for (int k = 0; k < 8; ++k) {
        short8 a[MT];
#pragma unroll
        for (int mt = 0; mt < MT; ++mt)
            a[mt] = *(const short8*)(&Xs[(mt * 16 + l15) * XS_STRIDE + k * 32 + q * 8]);
#pragma unroll
        for (int mt = 0; mt < MT; ++mt)
#pragma unroll
            for (int nt = 0; nt < 4; ++nt)
                acc[mt][nt] = __builtin_amdgcn_mfma_f32_16x16x32_bf16(
                    a[mt], bb[k & 1][nt], acc[mt][nt], 0, 0, 0);
        if (k + 2 < 8) {
#pragma unroll
            for (int nt = 0; nt < 4; ++nt)
                bb[k & 1][nt] = *(const short8*)(base + (size_t)(nt * 16) * nstride + kbase + (k + 2) * 32);
        }
    }
}

template<int MT>
__device__ __forceinline__ void elu_store_Xs(unsigned short* Xs,
                                             f32x4 (&acc)[MT][4],
                                             int n0, int l15, int q) {
#pragma unroll
    for (int mt = 0; mt < MT; ++mt)
#pragma unroll
        for (int nt = 0; nt < 4; ++nt)
#pragma unroll
            for (int r = 0; r < 4; ++r) {
                float h = acc[mt][nt][r];
                h = h > 0.f ? h : (__expf(h) - 1.f);
                Xs[(mt * 16 + q * 4 + r) * XS_STRIDE + n0 + nt * 16 + l15] = f32_to_bf16(h);
            }
}

// ---------------------------------------------------------------------------
// tree_level<MT>: R4-exact. block = 256 thr (4 waves), R = MT*16 rows x 256.
// MT=8: 2 waves/EU, dynamic LDS 67.6KB, unchunked 16-deep serial gathers.
// MT<8: 4 waves/EU, register gather prefetch overlapped with GEMM.
// ---------------------------------------------------------------------------
template<int MT>
__global__ __launch_bounds__(256, (MT == 8) ? 2 : 4)
void tree_level(const int* __restrict__ tokens,
                const unsigned short* __restrict__ Ebf,
                const unsigned short* __restrict__ Win,
                const unsigned short* __restrict__ W1,
                const unsigned short* __restrict__ W2,
                const float* __restrict__ b_in,
                const float* __restrict__ b1,
                const float* __restrict__ b2,
                const unsigned short* __restrict__ cur_in,
                unsigned short* __restrict__ cur_out,
                int L, int logL, int first)
{
    constexpr int R = MT * 16;
    constexpr int GITER = R / 8;
    constexpr bool PF = (MT < 8);
    extern __shared__ unsigned short Xs[];

    const int tid  = threadIdx.x;
    const int lane = tid & 63;
    const int wid  = tid >> 6;
    const int l15  = lane & 15;
    const int q    = lane >> 4;
    const int n0   = wid * 64;
    const int blk  = blockIdx.x;
    const int c    = tid & 31;
    const int sub  = tid >> 5;

    auto gsrc = [&](int p, int r) -> const unsigned short* {
        int g = blk * R + r;
        int b = g >> logL;
        int i = g - (b << logL);
        if (p == 0) {
            int tok = tokens[b * TOK_N + (L - 1) + i];
            return Ebf + (size_t)tok * 256;
        } else if (first) {
            int tok = tokens[b * TOK_N + 2047 + 2 * i + (p - 1)];
            return Ebf + (size_t)tok * 256;
        } else {
            return cur_in + ((size_t)b * (2 * L) + 2 * i + (p - 1)) * 256;
        }
    };

    // unchunked serial stage (MT==8): 16 loads in flight (R4-proven)
    auto stage = [&](int p) {
        short8 t[GITER];
#pragma unroll
        for (int it = 0; it < GITER; ++it)
            t[it] = *(const short8*)(gsrc(p, it * 8 + sub) + c * 8);
#pragma unroll
        for (int it = 0; it < GITER; ++it)
            *(short8*)(&Xs[(it * 8 + sub) * XS_STRIDE + c * 8]) = t[it];
    };

    f32x4 acc[MT][4];
    short8 g[PF ? GITER : 1];

    // ---- phase-0 gather (root) ------------------------------------------
    if constexpr (PF) {
#pragma unroll
        for (int it = 0; it < GITER; ++it)
            g[it] = *(const short8*)(gsrc(0, it * 8 + sub) + c * 8);
#pragma unroll
        for (int it = 0; it < GITER; ++it)
            *(short8*)(&Xs[(it * 8 + sub) * XS_STRIDE + c * 8]) = g[it];
    } else {
        stage(0);
    }
    __syncthreads();

    // ---- GEMM1: 3 phases of K=256 against Win (row stride 768) ----------
    acc_bias_init<MT>(acc, b_in, n0, l15);
    const unsigned short* wbase = Win + q * 8 + (size_t)(n0 + l15) * 768;
    for (int p = 0; p < 3; ++p) {
        if constexpr (PF) {
            if (p < 2) {
#pragma unroll
                for (int it = 0; it < GITER; ++it)
                    g[it] = *(const short8*)(gsrc(p + 1, it * 8 + sub) + c * 8);
            }
        }
        mfma_gemm<MT>(Xs, acc, wbase, 768, p * 256, l15, q);
        __syncthreads();
        if (p < 2) {
            if constexpr (PF) {
#pragma unroll
                for (int it = 0; it < GITER; ++it)
                    *(short8*)(&Xs[(it * 8 + sub) * XS_STRIDE + c * 8]) = g[it];
            } else {
                stage(p + 1);
            }
            __syncthreads();
        }
    }

    elu_store_Xs<MT>(Xs, acc, n0, l15, q);
    __syncthreads();

    // ---- GEMM2 (+ root re-gather prefetch if PF) ------------------------
    acc_bias_init<MT>(acc, b1, n0, l15);
    if constexpr (PF) {
#pragma unroll
        for (int it = 0; it < GITER; ++it)
            g[it] = *(const short8*)(gsrc(0, it * 8 + sub) + c * 8);
    }
    mfma_gemm<MT>(Xs, acc, W1 + q * 8 + (size_t)(n0 + l15) * 256, 256, 0, l15, q);
    __syncthreads();

    elu_store_Xs<MT>(Xs, acc, n0, l15, q);
    __syncthreads();

    // ---- GEMM3 ----------------------------------------------------------
    acc_bias_init<MT>(acc, b2, n0, l15);
    mfma_gemm<MT>(Xs, acc, W2 + q * 8 + (size_t)(n0 + l15) * 256, 256, 0, l15, q);
    __syncthreads();
    // park root rows (bf16) in Xs for transposed access by the epilogue
    if constexpr (PF) {
#pragma unroll
        for (int it = 0; it < GITER; ++it)
            *(short8*)(&Xs[(it * 8 + sub) * XS_STRIDE + c * 8]) = g[it];
    } else {
        stage(0);
    }
    __syncthreads();

    // ---- epilogue 3: out = root + H3, coalesced via LDS -----------------
#pragma unroll
    for (int mt = 0; mt < MT; ++mt)
#pragma unroll
        for (int r = 0; r < 4; ++r) {
            int row = mt * 16 + q * 4 + r;
#pragma unroll
            for (int nt = 0; nt < 4; ++nt) {
                int col = n0 + nt * 16 + l15;
                float o = acc[mt][nt][r] + bf16_to_f32(Xs[row * XS_STRIDE + col]);
                Xs[row * XS_STRIDE + col] = f32_to_bf16(o);
            }
        }
    __syncthreads();
#pragma unroll
    for (int it = 0; it < GITER; ++it) {
        int row = it * 8 + sub;
        *(short8*)(cur_out + ((size_t)(blk * R + row)) * 256 + c * 8) =
            *(const short8*)(&Xs[row * XS_STRIDE + c * 8]);
    }
}

// ---------------------------------------------------------------------------
// tree_tail: fused levels L=128..1. One block per batch element (64 blocks).
// Pv LDS region holds the previous level's output (<=128 rows x 256);
// left/right staging reads LDS, root gathers from Ebf. Only global output
// is the final fp32 row per batch. Rows i>=L are clamped duplicates
// (i & (L-1)); their outputs are masked at the Pv/final store.
// ---------------------------------------------------------------------------
__global__ __launch_bounds__(256, 2)
void tree_tail(const int* __restrict__ tokens,
               const unsigned short* __restrict__ Ebf,
               const unsigned short* __restrict__ Win,
               const unsigned short* __restrict__ W1,
               const unsigned short* __restrict__ W2,
               const float* __restrict__ b_in,
               const float* __restrict__ b1,
               const float* __restrict__ b2,
               const unsigned short* __restrict__ cur_in,  // L=256 output
               float* __restrict__ final_out)
{
    constexpr int MT = 8;
    constexpr int GITER = 16;
    extern __shared__ unsigned short lds[];
    unsigned short* Xs = lds;                       // [128][XS_STRIDE]
    unsigned short* Pv = lds + 128 * XS_STRIDE;     // [128][256] prev output

    const int tid  = threadIdx.x;
    const int lane = tid & 63;
    const int wid  = tid >> 6;
    const int l15  = lane & 15;
    const int q    = lane >> 4;
    const int n0   = wid * 64;
    const int b    = blockIdx.x;                    // batch element
    const int c    = tid & 31;
    const int sub  = tid >> 5;

    f32x4 acc[MT][4];

    for (int L = 128; L >= 1; L >>= 1) {
        const int Lm = L - 1;

        auto src = [&](int p, int i) -> const unsigned short* {
            int il = i & Lm;                        // clamp duplicate rows
            if (p == 0) {
                int tok = tokens[b * TOK_N + (L - 1) + il];
                return Ebf + (size_t)tok * 256;
            }
            if (L == 128)                           // first fused level: global
                return cur_in + ((size_t)b * 256 + 2 * il + (p - 1)) * 256;
            return Pv + (2 * il + (p - 1)) * 256;   // LDS
        };
        auto stg = [&](int p) {
            short8 t[GITER];
#pragma unroll
            for (int it = 0; it < GITER; ++it)
                t[it] = *(const short8*)(src(p, it * 8 + sub) + c * 8);
#pragma unroll
            for (int it = 0; it < GITER; ++it)
                *(short8*)(&Xs[(it * 8 + sub) * XS_STRIDE + c * 8]) = t[it];
        };

        stg(0);
        __syncthreads();

        acc_bias_init<MT>(acc, b_in, n0, l15);
        const unsigned short* wbase = Win + q * 8 + (size_t)(n0 + l15) * 768;
        for (int p = 0; p < 3; ++p) {
            mfma_gemm<MT>(Xs, acc, wbase, 768, p * 256, l15, q);
            __syncthreads();
            if (p < 2) { stg(p + 1); __syncthreads(); }
        }

        elu_store_Xs<MT>(Xs, acc, n0, l15, q);
        __syncthreads();

        acc_bias_init<MT>(acc, b1, n0, l15);
        mfma_gemm<MT>(Xs, acc, W1 + q * 8 + (size_t)(n0 + l15) * 256, 256, 0, l15, q);
        __syncthreads();

        elu_store_Xs<MT>(Xs, acc, n0, l15, q);
        __syncthreads();

        acc_bias_init<MT>(acc, b2, n0, l15);
        mfma_gemm<MT>(Xs, acc, W2 + q * 8 + (size_t)(n0 + l15) * 256, 256, 0, l15, q);
        __syncthreads();
        stg(0);                                      // root re-park in Xs
        __syncthreads();

        // epilogue: out = root + H3; write masked rows to Pv (or final)
        if (L == 1) {
#pragma unroll
            for (int mt = 0; mt < MT; ++mt)
#pragma unroll
                for (int r = 0; r < 4; ++r) {
                    int row = mt * 16 + q * 4 + r;
                    if (row == 0) {
#pragma unroll
                        for (int nt = 0; nt < 4; ++nt) {
                            int col = n0 + nt * 16 + l15;
                            final_out[(size_t)b * 256 + col] =
                                acc[mt][nt][r] + bf16_to_f32(Xs[row * XS_STRIDE + col]);
                        }
                    }
                }
        } else {
#pragma unroll
            for (int mt = 0; mt < MT; ++mt)
#pragma unroll
                for (int r = 0; r < 4; ++r) {
                    int row = mt * 16 + q * 4 + r;
                    if (row < L) {
#pragma unroll
                        for (int nt = 0; nt < 4; ++nt) {
                            int col = n0 + nt * 16 + l15;
                            float o = acc[mt][nt][r] + bf16_to_f32(Xs[row * XS_STRIDE + col]);
                            Pv[row * 256 + col] = f32_to_bf16(o);
                        }
                    }
                }
        }
        __syncthreads();   // Pv complete before next level stages from it
    }
}

extern "C" void kernel_launch(void* const* d_in, const int* in_sizes, int n_in,
                              void* d_out, int out_size, void* d_ws, size_t ws_size,
                              hipStream_t stream) {
    const int*   tokens = (const int*)  d_in[0];
    const float* E      = (const float*)d_in[1];
    const float* W_in   = (const float*)d_in[2];
    const float* b_in   = (const float*)d_in[3];
    const float* W1     = (const float*)d_in[4];
    const float* b1     = (const float*)d_in[5];
    const float* W2     = (const float*)d_in[6];
    const float* b2     = (const float*)d_in[7];
    float* out = (float*)d_out;
    char* ws = (char*)d_ws;

    unsigned short* Ebf   = (unsigned short*)(ws);
    unsigned short* Winbf = (unsigned short*)(ws + 16416768);
    unsigned short* W1bf  = (unsigned short*)(ws + 16809984);
    unsigned short* W2bf  = (unsigned short*)(ws + 16941056);
    unsigned short* curA  = (unsigned short*)(ws + 17072128);
    unsigned short* curB  = (unsigned short*)(ws + 50626560);

    // allow >64KB dynamic LDS (once per process)
    static bool attr_done = false;
    if (!attr_done) {
        void (*k8)(const int*, const unsigned short*, const unsigned short*,
                   const unsigned short*, const unsigned short*, const float*,
                   const float*, const float*, const unsigned short*,
                   unsigned short*, int, int, int) = tree_level<8>;
        (void)hipFuncSetAttribute(reinterpret_cast<const void*>(k8),
                                  hipFuncAttributeMaxDynamicSharedMemorySize,
                                  128 * XS_STRIDE * 2);
        (void)hipFuncSetAttribute(reinterpret_cast<const void*>(&tree_tail),
                                  hipFuncAttributeMaxDynamicSharedMemorySize,
                                  128 * XS_STRIDE * 2 + 128 * 256 * 2);
        attr_done = true;
    }

    convert_f32_bf16<<<1024, 256, 0, stream>>>(E, W_in, W1, W2,
                                               Ebf, Winbf, W1bf, W2bf);

    // L=1024 (first level, reads tokens): MT=8, 512 blocks -> curA
    tree_level<8><<<dim3(512), dim3(256), 128 * XS_STRIDE * 2, stream>>>(
        tokens, Ebf, Winbf, W1bf, W2bf, b_in, b1, b2,
        nullptr, curA, 1024, 10, 1);
    // L=512: MT=8, 256 blocks, curA -> curB
    tree_level<8><<<dim3(256), dim3(256), 128 * XS_STRIDE * 2, stream>>>(
        tokens, Ebf, Winbf, W1bf, W2bf, b_in, b1, b2,
        curA, curB, 512, 9, 0);
    // L=256: MT=2, 512 blocks, curB -> curA
    tree_level<2><<<dim3(512), dim3(256), 32 * XS_STRIDE * 2, stream>>>(
        tokens, Ebf, Winbf, W1bf, W2bf, b_in, b1, b2,
        curB, curA, 256, 8, 0);
    // fused tail L=128..1: 64 blocks (one per batch), curA -> out
    tree_tail<<<dim3(64), dim3(256), 128 * XS_STRIDE * 2 + 128 * 256 * 2, stream>>>(
        tokens, Ebf, Winbf, W1bf, W2bf, b_in, b1, b2, curA, out);
}